// Round 1
// baseline (282.817 us; speedup 1.0000x reference)
//
#include <hip/hip_runtime.h>
#include <math.h>

// Problem constants
#define B_  4
#define C_  16
#define T_  32
#define H_  128
#define W_  128
#define KF  4
#define TAU 0.1
#define EPS2 (1e-6f * 1e-6f)

// Derived
#define HW4   ((H_ * W_) / 4)          // 4096 float4 per (b,c,t) slice
#define NCOLS (B_ * C_ * HW4)          // 262144 float4-columns
#define N_MAIN ((double)B_ * C_ * T_ * H_ * W_)        // 33554432
#define N_TEMP ((double)B_ * C_ * (T_ - 1) * H_ * W_)  // 32505856

struct Consts {
    float D[KF][T_];   // truncated orthonormal DCT-II rows
    float M[KF][KF];   // quadratic form for temporal-diff MSE
};

__global__ __launch_bounds__(256)
void loss_main_kernel(const float4* __restrict__ xs,
                      const float4* __restrict__ xt,
                      double* __restrict__ acc,
                      Consts con)
{
    const int p  = blockIdx.x * 256 + threadIdx.x;   // [0, NCOLS)
    const int bc = p >> 12;                          // p / 4096
    const int hw = p & 4095;                         // p % 4096
    const size_t base = (size_t)bc * (T_ * HW4) + hw;
    const float4* A  = xs + base;
    const float4* Bp = xt + base;

    float charb = 0.f;
    float c[KF][4];
    #pragma unroll
    for (int n = 0; n < KF; ++n)
        #pragma unroll
        for (int j = 0; j < 4; ++j) c[n][j] = 0.f;

    #pragma unroll
    for (int t = 0; t < T_; ++t) {
        float4 a = A[(size_t)t * HW4];
        float4 b = Bp[(size_t)t * HW4];
        float d[4];
        d[0] = a.x - b.x; d[1] = a.y - b.y; d[2] = a.z - b.z; d[3] = a.w - b.w;
        #pragma unroll
        for (int j = 0; j < 4; ++j)
            charb += sqrtf(fmaf(d[j], d[j], EPS2));
        #pragma unroll
        for (int n = 0; n < KF; ++n) {
            const float w = con.D[n][t];
            #pragma unroll
            for (int j = 0; j < 4; ++j)
                c[n][j] = fmaf(w, d[j], c[n][j]);
        }
    }

    // Temporal-diff MSE per column: c^T M c  (row/col 0 of M are zero: DC row)
    float quad = 0.f;
    #pragma unroll
    for (int j = 0; j < 4; ++j) {
        #pragma unroll
        for (int n = 1; n < KF; ++n) {
            float e = 0.f;
            #pragma unroll
            for (int m = 1; m < KF; ++m)
                e = fmaf(con.M[n][m], c[m][j], e);
            quad = fmaf(c[n][j], e, quad);
        }
    }

    // Wave (64-lane) shuffle reduction
    #pragma unroll
    for (int off = 32; off > 0; off >>= 1) {
        charb += __shfl_down(charb, off, 64);
        quad  += __shfl_down(quad,  off, 64);
    }

    __shared__ float s_ch[4], s_q[4];
    const int lane = threadIdx.x & 63;
    const int wave = threadIdx.x >> 6;
    if (lane == 0) { s_ch[wave] = charb; s_q[wave] = quad; }
    __syncthreads();

    if (threadIdx.x == 0) {
        double ch = (double)s_ch[0] + (double)s_ch[1] + (double)s_ch[2] + (double)s_ch[3];
        double q  = (double)s_q[0]  + (double)s_q[1]  + (double)s_q[2]  + (double)s_q[3];
        atomicAdd(&acc[0], ch);
        atomicAdd(&acc[1], q);
    }
}

__global__ void loss_final_kernel(const double* __restrict__ acc,
                                  float* __restrict__ out)
{
    if (threadIdx.x == 0) {
        double Lm = acc[0] / N_MAIN;
        double Lt = acc[1] / N_TEMP;
        out[0] = (float)(Lm + TAU * Lt);
        out[1] = (float)Lm;
        out[2] = (float)Lt;
    }
}

extern "C" void kernel_launch(void* const* d_in, const int* in_sizes, int n_in,
                              void* d_out, int out_size, void* d_ws, size_t ws_size,
                              hipStream_t stream)
{
    const float4* xs = (const float4*)d_in[0];
    const float4* xt = (const float4*)d_in[1];
    float* out = (float*)d_out;
    double* acc = (double*)d_ws;

    // Build DCT constants on host (cheap, deterministic, every call)
    Consts con;
    for (int n = 0; n < KF; ++n) {
        for (int t = 0; t < T_; ++t) {
            double v = sqrt(2.0 / (double)T_) *
                       cos(M_PI * (2.0 * t + 1.0) * n / (2.0 * T_));
            if (n == 0) v *= 1.0 / sqrt(2.0);
            con.D[n][t] = (float)v;
        }
    }
    for (int n = 0; n < KF; ++n) {
        for (int m = 0; m < KF; ++m) {
            double s = 0.0;
            for (int ss = 0; ss < T_ - 1; ++ss) {
                double en = (double)con.D[n][ss + 1] - (double)con.D[n][ss];
                double em = (double)con.D[m][ss + 1] - (double)con.D[m][ss];
                s += en * em;
            }
            con.M[n][m] = (float)s;
        }
    }

    // Zero the two double accumulators (d_ws is poisoned 0xAA before each call)
    hipMemsetAsync(d_ws, 0, 2 * sizeof(double), stream);

    loss_main_kernel<<<NCOLS / 256, 256, 0, stream>>>(xs, xt, acc, con);
    loss_final_kernel<<<1, 64, 0, stream>>>(acc, out);
}